// Round 17
// baseline (5440.146 us; speedup 1.0000x reference)
//
#include <hip/hip_runtime.h>
#include <hip/hip_fp16.h>

typedef __attribute__((ext_vector_type(8))) short s16x8;
typedef __attribute__((ext_vector_type(8))) _Float16 f16x8;
typedef __attribute__((ext_vector_type(4))) float f32x4;

// ---------------------------------------------------------------------------
// Pack 8 int32 (values 0..15) -> 1 uint32 of nibbles (k ascending from LSB).
// ---------------------------------------------------------------------------
__global__ void pack_kernel(const int* __restrict__ q, uint32_t* __restrict__ p,
                            long n8) {
  long i = (long)blockIdx.x * blockDim.x + threadIdx.x;
  long stride = (long)gridDim.x * blockDim.x;
  for (; i < n8; i += stride) {
    int4 a = ((const int4*)q)[2 * i];
    int4 b = ((const int4*)q)[2 * i + 1];
    uint32_t w = (uint32_t)a.x | ((uint32_t)a.y << 4) | ((uint32_t)a.z << 8) |
                 ((uint32_t)a.w << 12) | ((uint32_t)b.x << 16) |
                 ((uint32_t)b.y << 20) | ((uint32_t)b.z << 24) |
                 ((uint32_t)b.w << 28);
    p[i] = w;
  }
}

// ---------------------------------------------------------------------------
// Dequant: f16(64+q)=0x5400|(q<<4);  w = b*s - (64+z)*s
// ---------------------------------------------------------------------------
__device__ __forceinline__ s16x8 dq_compute(int4 q0, int4 q1, float s, float z) {
  __half hs = __float2half(s);
  __half2 s2 = __halves2half2(hs, hs);
  __half hc = __float2half(-(64.f + z) * s);
  __half2 c2 = __halves2half2(hc, hc);
  uint32_t b0 = 0x54005400u + ((uint32_t)q0.x << 4) + ((uint32_t)q0.y << 20);
  uint32_t b1 = 0x54005400u + ((uint32_t)q0.z << 4) + ((uint32_t)q0.w << 20);
  uint32_t b2 = 0x54005400u + ((uint32_t)q1.x << 4) + ((uint32_t)q1.y << 20);
  uint32_t b3 = 0x54005400u + ((uint32_t)q1.z << 4) + ((uint32_t)q1.w << 20);
  union { s16x8 v; __half2 h2[4]; } w;
  w.h2[0] = __hfma2(*(__half2*)&b0, s2, c2);
  w.h2[1] = __hfma2(*(__half2*)&b1, s2, c2);
  w.h2[2] = __hfma2(*(__half2*)&b2, s2, c2);
  w.h2[3] = __hfma2(*(__half2*)&b3, s2, c2);
  return w.v;
}

// 8 weights from one packed u32 (nibbles ascending)
__device__ __forceinline__ s16x8 dq8(uint32_t w, __half2 s2, __half2 c2) {
  union { s16x8 v; __half2 h2[4]; } r;
#pragma unroll
  for (int i = 0; i < 4; ++i) {
    uint32_t t = (w >> (8 * i)) & 0xFFu;
    uint32_t b = 0x54005400u + ((t & 15u) << 4) + ((t >> 4) << 20);
    r.h2[i] = __hfma2(*(__half2*)&b, s2, c2);
  }
  return r.v;
}

// bijective XCD swizzle (m204)
__device__ __forceinline__ int xcd_swz(int w0, int nwg) {
  const int q = nwg >> 3, r = nwg & 7;
  const int xcd = w0 & 7, idx = w0 >> 3;
  const int base = (xcd < r) ? xcd * (q + 1) : r * (q + 1) + (xcd - r) * q;
  return base + idx;
}

// ---------------------------------------------------------------------------
// gate/up GEMM, M-chunked, full-I: P = x @ Wq^T (dequant inline).
// A: fp32 x reg-staged, cvt->fp16, swizzled ds_write (1-deep; x chunk L3-hot).
// B: 2-deep Q prefetch + dequant. PK=1: 4-bit packed weights.
// EPI=0: Pan = fp16(acc).  EPI=1: Pan = silu(Pan) * acc  (in-place h)
// BM=256, BN=128, BK=64. 512 thr (8 waves: 4M x 2N).
// ---------------------------------------------------------------------------
template <int EPI, int PK>
__global__ __launch_bounds__(512, 2)
void qgemm_x_kernel(const float* __restrict__ X,
                    const int* __restrict__ Q, const uint32_t* __restrict__ QP,
                    const float* __restrict__ S, const float* __restrict__ Z,
                    __half* __restrict__ Pan, int mbs) {
  constexpr int H = 4096, I = 11008, G = 32;
  const int wg = xcd_swz(blockIdx.x, gridDim.x);
  const int mb = wg % mbs;
  const int nb = wg / mbs;
  const int m0 = mb * 256;
  const int n0 = nb * 128;
  const int tid = threadIdx.x;
  const int lane = tid & 63;
  const int wave = tid >> 6;
  const int wm = (wave >> 1) * 64, wn = (wave & 1) * 64;
  const int l15 = lane & 15, lq = lane >> 4;
  const int rsw = (l15 & 7) << 3;

  __shared__ __half As[2][256][64];   // 64 KB
  __shared__ __half Bs[2][128][64];   // 32 KB

  f32x4 acc[4][4];
#pragma unroll
  for (int i = 0; i < 4; ++i)
#pragma unroll
    for (int j = 0; j < 4; ++j) acc[i][j] = {0.f, 0.f, 0.f, 0.f};

  // A staging: row tid>>1 (0..255), 32 cols at (tid&1)*32. fp32 -> fp16.
  const int arow = tid >> 1, acol0 = (tid & 1) * 32, asw = (arow & 7) << 3;
  const float* aP = X + (size_t)(m0 + arow) * H + acol0;
  // B staging: 512 thr cover 128 rows x 64 cols
  const int qrow = tid >> 2, qcol0 = (tid & 3) * 16, qsw = (qrow & 7) << 3;
  const int*      qP  = Q  + (size_t)(n0 + qrow) * H + qcol0;
  const uint32_t* qPp = QP + (size_t)(n0 + qrow) * (H / 8) + (tid & 3) * 2;
  const float* sP = S + (size_t)(n0 + qrow) * G;
  const float* zP = Z + (size_t)(n0 + qrow) * G;

  float4 a4[8];
  int4 qA[4], qB[4];
  uint32_t wA0, wA1, wB0, wB1;
  float sA, zA, sB, zB;

#define LOAD_A(kk)                                                    \
  {                                                                   \
    const int _k = (kk);                                              \
    _Pragma("unroll")                                                 \
    for (int i = 0; i < 8; ++i) a4[i] = ((const float4*)(aP + _k))[i];\
  }
#define WRITE_A(buf)                                                  \
  {                                                                   \
    _Pragma("unroll")                                                 \
    for (int i = 0; i < 4; ++i) {                                     \
      union { s16x8 v; __half2 h2[4]; } u;                            \
      u.h2[0] = __floats2half2_rn(a4[2 * i].x, a4[2 * i].y);          \
      u.h2[1] = __floats2half2_rn(a4[2 * i].z, a4[2 * i].w);          \
      u.h2[2] = __floats2half2_rn(a4[2 * i + 1].x, a4[2 * i + 1].y);  \
      u.h2[3] = __floats2half2_rn(a4[2 * i + 1].z, a4[2 * i + 1].w);  \
      *(s16x8*)&As[buf][arow][(acol0 + i * 8) ^ asw] = u.v;           \
    }                                                                 \
  }
#define LOAD_Q(set, kk)                                               \
  {                                                                   \
    const int _k = (kk);                                              \
    if (PK) {                                                         \
      w##set##0 = qPp[_k >> 3]; w##set##1 = qPp[(_k >> 3) + 1];       \
    } else {                                                          \
      _Pragma("unroll")                                               \
      for (int i = 0; i < 4; ++i) q##set[i] = ((const int4*)(qP + _k))[i]; \
    }                                                                 \
    s##set = sP[_k >> 7]; z##set = zP[_k >> 7];                       \
  }
#define WRITE_B(buf, set)                                             \
  {                                                                   \
    if (PK) {                                                         \
      __half hs = __float2half(s##set);                               \
      __half2 s2 = __halves2half2(hs, hs);                            \
      __half hc = __float2half(-(64.f + z##set) * s##set);            \
      __half2 c2 = __halves2half2(hc, hc);                            \
      *(s16x8*)&Bs[buf][qrow][(qcol0 + 0) ^ qsw] = dq8(w##set##0, s2, c2); \
      *(s16x8*)&Bs[buf][qrow][(qcol0 + 8) ^ qsw] = dq8(w##set##1, s2, c2); \
    } else {                                                          \
      *(s16x8*)&Bs[buf][qrow][(qcol0 + 0) ^ qsw] = dq_compute(q##set[0], q##set[1], s##set, z##set); \
      *(s16x8*)&Bs[buf][qrow][(qcol0 + 8) ^ qsw] = dq_compute(q##set[2], q##set[3], s##set, z##set); \
    }                                                                 \
  }
#define MFMA_BUF(buf)                                                 \
  {                                                                   \
    __builtin_amdgcn_s_setprio(1);                                    \
    _Pragma("unroll")                                                 \
    for (int kk = 0; kk < 2; ++kk) {                                  \
      const int cbase = (kk * 32 + lq * 8) ^ rsw;                     \
      f16x8 af[4];                                                    \
      _Pragma("unroll")                                               \
      for (int i = 0; i < 4; ++i)                                     \
        af[i] = *(const f16x8*)&As[buf][wm + i * 16 + l15][cbase];    \
      _Pragma("unroll")                                               \
      for (int j = 0; j < 4; ++j) {                                   \
        f16x8 bf = *(const f16x8*)&Bs[buf][wn + j * 16 + l15][cbase]; \
        _Pragma("unroll")                                             \
        for (int i = 0; i < 4; ++i)                                   \
          acc[i][j] = __builtin_amdgcn_mfma_f32_16x16x32_f16(af[i], bf, acc[i][j], 0, 0, 0); \
      }                                                               \
    }                                                                 \
    __builtin_amdgcn_s_setprio(0);                                    \
  }

  const int nt = H / 64;  // 64, even
  LOAD_A(0)
  LOAD_Q(A, 0)
  LOAD_Q(B, 64)
  WRITE_A(0)
  WRITE_B(0, A)
  __syncthreads();

  for (int t = 0; t < nt; t += 2) {
    if (t + 1 < nt) LOAD_A((t + 1) * 64)
    if (t + 2 < nt) LOAD_Q(A, (t + 2) * 64)
    MFMA_BUF(0)
    if (t + 1 < nt) { WRITE_A(1) WRITE_B(1, B) }
    __syncthreads();
    if (t + 2 < nt) LOAD_A((t + 2) * 64)
    if (t + 3 < nt) LOAD_Q(B, (t + 3) * 64)
    MFMA_BUF(1)
    if (t + 2 < nt) { WRITE_A(0) WRITE_B(0, A) }
    __syncthreads();
  }
#undef LOAD_A
#undef WRITE_A
#undef LOAD_Q
#undef WRITE_B
#undef MFMA_BUF

#pragma unroll
  for (int i = 0; i < 4; ++i)
#pragma unroll
    for (int j = 0; j < 4; ++j)
#pragma unroll
      for (int r = 0; r < 4; ++r) {
        const int row = m0 + wm + i * 16 + lq * 4 + r;
        const int col = n0 + wn + j * 16 + l15;
        const size_t idx = (size_t)row * I + col;
        if (EPI == 0) {
          Pan[idx] = __float2half(acc[i][j][r]);
        } else {
          float g = __half2float(Pan[idx]);
          float u = acc[i][j][r];
          Pan[idx] = __float2half((g / (1.f + __expf(-g))) * u);
        }
      }
}

// ---------------------------------------------------------------------------
// Down GEMM (r14 structure): out = h @ Wd^T. A (h fp16) via global_load_lds.
// ---------------------------------------------------------------------------
template <int PK>
__global__ __launch_bounds__(512, 2)
void down_kernel(const __half* __restrict__ Hws,
                 const int* __restrict__ Qd, const uint32_t* __restrict__ QdP,
                 const float* __restrict__ Sd, const float* __restrict__ Zd,
                 float* __restrict__ Out, int mbs) {
  constexpr int K = 11008, N = 4096, G = 86;
  const int wg = xcd_swz(blockIdx.x, gridDim.x);
  const int mb = wg % mbs;
  const int nb = wg / mbs;
  const int m0 = mb * 256, n0 = nb * 128;
  const int tid = threadIdx.x;
  const int lane = tid & 63;
  const int wave = tid >> 6;
  const int wm = (wave >> 1) * 64, wn = (wave & 1) * 64;
  const int l15 = lane & 15, lq = lane >> 4;
  const int rsw = (l15 & 7) << 3;

  __shared__ __half As[2][256][64];
  __shared__ __half Bs[2][128][64];

  f32x4 acc[4][4];
#pragma unroll
  for (int i = 0; i < 4; ++i)
#pragma unroll
    for (int j = 0; j < 4; ++j) acc[i][j] = {0.f, 0.f, 0.f, 0.f};

  const int arowD = tid >> 3;
  const int acolD = (((tid & 7) ^ ((tid >> 3) & 7)) << 3);
  const int qrow = tid >> 2, qcol0 = (tid & 3) * 16, qsw = (qrow & 7) << 3;
  const int*      qP  = Qd  + (size_t)(n0 + qrow) * K + qcol0;
  const uint32_t* qPp = QdP + (size_t)(n0 + qrow) * (K / 8) + (tid & 3) * 2;
  const float* sP = Sd + (size_t)(n0 + qrow) * G;
  const float* zP = Zd + (size_t)(n0 + qrow) * G;

  int4 qA[4], qB[4];
  uint32_t wA0, wA1, wB0, wB1;
  float sA, zA, sB, zB;

#define STAGE_A(buf, kk)                                              \
  {                                                                   \
    const int _k = (kk);                                              \
    _Pragma("unroll")                                                 \
    for (int c = 0; c < 4; ++c) {                                     \
      const __half* src = Hws + (size_t)(m0 + c * 64 + arowD) * K + _k + acolD; \
      __half* dst = &As[buf][0][0] + (size_t)(c * 512 + tid) * 8;     \
      __builtin_amdgcn_global_load_lds((const __attribute__((address_space(1))) void*)src, \
                                       (__attribute__((address_space(3))) void*)dst, 16, 0, 0); \
    }                                                                 \
  }
#define LOAD_Q(set, kk)                                               \
  {                                                                   \
    const int _k = (kk);                                              \
    if (PK) {                                                         \
      w##set##0 = qPp[_k >> 3]; w##set##1 = qPp[(_k >> 3) + 1];       \
    } else {                                                          \
      _Pragma("unroll")                                               \
      for (int i = 0; i < 4; ++i) q##set[i] = ((const int4*)(qP + _k))[i]; \
    }                                                                 \
    s##set = sP[_k >> 7]; z##set = zP[_k >> 7];                       \
  }
#define WRITE_B(buf, set)                                             \
  {                                                                   \
    if (PK) {                                                         \
      __half hs = __float2half(s##set);                               \
      __half2 s2 = __halves2half2(hs, hs);                            \
      __half hc = __float2half(-(64.f + z##set) * s##set);            \
      __half2 c2 = __halves2half2(hc, hc);                            \
      *(s16x8*)&Bs[buf][qrow][(qcol0 + 0) ^ qsw] = dq8(w##set##0, s2, c2); \
      *(s16x8*)&Bs[buf][qrow][(qcol0 + 8) ^ qsw] = dq8(w##set##1, s2, c2); \
    } else {                                                          \
      *(s16x8*)&Bs[buf][qrow][(qcol0 + 0) ^ qsw] = dq_compute(q##set[0], q##set[1], s##set, z##set); \
      *(s16x8*)&Bs[buf][qrow][(qcol0 + 8) ^ qsw] = dq_compute(q##set[2], q##set[3], s##set, z##set); \
    }                                                                 \
  }
#define MFMA_BUF(buf)                                                 \
  {                                                                   \
    __builtin_amdgcn_s_setprio(1);                                    \
    _Pragma("unroll")                                                 \
    for (int kk = 0; kk < 2; ++kk) {                                  \
      const int cbase = (kk * 32 + lq * 8) ^ rsw;                     \
      f16x8 af[4];                                                    \
      _Pragma("unroll")                                               \
      for (int i = 0; i < 4; ++i)                                     \
        af[i] = *(const f16x8*)&As[buf][wm + i * 16 + l15][cbase];    \
      _Pragma("unroll")                                               \
      for (int j = 0; j < 4; ++j) {                                   \
        f16x8 bf = *(const f16x8*)&Bs[buf][wn + j * 16 + l15][cbase]; \
        _Pragma("unroll")                                             \
        for (int i = 0; i < 4; ++i)                                   \
          acc[i][j] = __builtin_amdgcn_mfma_f32_16x16x32_f16(af[i], bf, acc[i][j], 0, 0, 0); \
      }                                                               \
    }                                                                 \
    __builtin_amdgcn_s_setprio(0);                                    \
  }

  const int nt = K / 64;  // 172, even
  STAGE_A(0, 0)
  LOAD_Q(A, 0)
  LOAD_Q(B, 64)
  WRITE_B(0, A)
  __syncthreads();

  for (int t = 0; t < nt; t += 2) {
    if (t + 1 < nt) STAGE_A(1, (t + 1) * 64)
    if (t + 2 < nt) LOAD_Q(A, (t + 2) * 64)
    MFMA_BUF(0)
    if (t + 1 < nt) WRITE_B(1, B)
    __syncthreads();
    if (t + 2 < nt) STAGE_A(0, (t + 2) * 64)
    if (t + 3 < nt) LOAD_Q(B, (t + 3) * 64)
    MFMA_BUF(1)
    if (t + 2 < nt) WRITE_B(0, A)
    __syncthreads();
  }
#undef STAGE_A
#undef LOAD_Q
#undef WRITE_B
#undef MFMA_BUF

#pragma unroll
  for (int i = 0; i < 4; ++i)
#pragma unroll
    for (int j = 0; j < 4; ++j)
#pragma unroll
      for (int r = 0; r < 4; ++r) {
        const int row = m0 + wm + i * 16 + lq * 4 + r;
        const int col = n0 + wn + j * 16 + l15;
        Out[(size_t)row * N + col] = acc[i][j][r];
      }
}

// ---------------------------------------------------------------------------
extern "C" void kernel_launch(void* const* d_in, const int* in_sizes, int n_in,
                              void* d_out, int out_size, void* d_ws, size_t ws_size,
                              hipStream_t stream) {
  const float* x  = (const float*)d_in[0];
  const int* qg   = (const int*)d_in[1];
  const int* qu   = (const int*)d_in[2];
  const int* qd   = (const int*)d_in[3];
  const float* sg = (const float*)d_in[4];
  const float* zg = (const float*)d_in[5];
  const float* su = (const float*)d_in[6];
  const float* zu = (const float*)d_in[7];
  const float* sd = (const float*)d_in[8];
  const float* zd = (const float*)d_in[9];
  float* out = (float*)d_out;

  const int M = 8192, H = 4096, I = 11008;
  const long N8 = (long)I * H / 8;       // 5,636,096 u32 = 1376 out-rows each
  const int PG_ROW = 4064;               // Pg at rows 4064..5439
  const int PU_ROW = PG_ROW + 1376;      // Pu at rows 5440..6815
  const int PD_ROW = PU_ROW + 1376;      // Pd at rows 6816..8191

  uint32_t* Pg = (uint32_t*)((char*)d_out + (size_t)PG_ROW * H * 4);
  uint32_t* Pu = Pg + N8;
  uint32_t* Pd = Pu + N8;

  pack_kernel<<<2048, 256, 0, stream>>>(qg, Pg, N8);
  pack_kernel<<<2048, 256, 0, stream>>>(qu, Pu, N8);
  pack_kernel<<<2048, 256, 0, stream>>>(qd, Pd, N8);

  // ws holds only the h panel: Mc rows x I fp16.
  long mc = (long)(ws_size / ((size_t)I * 2));
  mc &= ~255L;
  if (mc > 2048) mc = 2048;   // mbs=8 -> down grid exactly 256
  if (mc < 256) mc = 256;
  const int Mc = (int)mc;

  __half* wsh = (__half*)d_ws;

  for (int mbase = 0; mbase < M; mbase += Mc) {
    const int rows = (M - mbase < Mc) ? (M - mbase) : Mc;
    const int mbs = rows / 256;
    // Packed-usability: prior chunks wrote rows [0, mbase). A packed matrix is
    // readable iff untouched so far; down additionally must not overwrite the
    // region it is reading (gate/up never write d_out; each chunk's gemms read
    // before its own down writes).
    const bool g_pk = (mbase <= PG_ROW);
    const bool u_pk = (mbase <= PU_ROW);
    const bool d_pk = (mbase + rows <= PD_ROW);

    if (g_pk)
      qgemm_x_kernel<0, 1><<<mbs * (I / 128), 512, 0, stream>>>(
          x + (size_t)mbase * H, qg, Pg, sg, zg, wsh, mbs);
    else
      qgemm_x_kernel<0, 0><<<mbs * (I / 128), 512, 0, stream>>>(
          x + (size_t)mbase * H, qg, Pg, sg, zg, wsh, mbs);

    if (u_pk)
      qgemm_x_kernel<1, 1><<<mbs * (I / 128), 512, 0, stream>>>(
          x + (size_t)mbase * H, qu, Pu, su, zu, wsh, mbs);
    else
      qgemm_x_kernel<1, 0><<<mbs * (I / 128), 512, 0, stream>>>(
          x + (size_t)mbase * H, qu, Pu, su, zu, wsh, mbs);

    if (d_pk)
      down_kernel<1><<<mbs * (H / 128), 512, 0, stream>>>(
          wsh, qd, Pd, sd, zd, out + (size_t)mbase * H, mbs);
    else
      down_kernel<0><<<mbs * (H / 128), 512, 0, stream>>>(
          wsh, qd, Pd, sd, zd, out + (size_t)mbase * H, mbs);
  }
}

// Round 18
// 3612.111 us; speedup vs baseline: 1.5061x; 1.5061x over previous
//
#include <hip/hip_runtime.h>
#include <hip/hip_fp16.h>

typedef __attribute__((ext_vector_type(8))) short s16x8;
typedef __attribute__((ext_vector_type(8))) _Float16 f16x8;
typedef __attribute__((ext_vector_type(4))) float f32x4;

// ---------------------------------------------------------------------------
// fp32 -> fp16 conversion (vectorized, grid-stride)
// ---------------------------------------------------------------------------
__global__ void cvt_f32_to_f16_kernel(const float* __restrict__ in,
                                      __half* __restrict__ out, long n) {
  long i = (long)blockIdx.x * blockDim.x + threadIdx.x;
  long stride = (long)gridDim.x * blockDim.x;
  const float4* p4 = (const float4*)in;
  for (long j = i; j * 8 < n; j += stride) {
    float4 a = p4[j * 2];
    float4 b = p4[j * 2 + 1];
    union { s16x8 v; __half2 h2[4]; } w;
    w.h2[0] = __floats2half2_rn(a.x, a.y);
    w.h2[1] = __floats2half2_rn(a.z, a.w);
    w.h2[2] = __floats2half2_rn(b.x, b.y);
    w.h2[3] = __floats2half2_rn(b.z, b.w);
    *(s16x8*)(out + j * 8) = w.v;
  }
}

// ---------------------------------------------------------------------------
// Pack 8 int32 (values 0..15) -> 1 uint32 of nibbles (k ascending from LSB).
// ---------------------------------------------------------------------------
__global__ void pack_kernel(const int* __restrict__ q, uint32_t* __restrict__ p,
                            long n8) {
  long i = (long)blockIdx.x * blockDim.x + threadIdx.x;
  long stride = (long)gridDim.x * blockDim.x;
  for (; i < n8; i += stride) {
    int4 a = ((const int4*)q)[2 * i];
    int4 b = ((const int4*)q)[2 * i + 1];
    uint32_t w = (uint32_t)a.x | ((uint32_t)a.y << 4) | ((uint32_t)a.z << 8) |
                 ((uint32_t)a.w << 12) | ((uint32_t)b.x << 16) |
                 ((uint32_t)b.y << 20) | ((uint32_t)b.z << 24) |
                 ((uint32_t)b.w << 28);
    p[i] = w;
  }
}

// ---------------------------------------------------------------------------
// Dequant: f16(64+q)=0x5400|(q<<4);  w = b*s - (64+z)*s
// ---------------------------------------------------------------------------
__device__ __forceinline__ s16x8 dq_compute(int4 q0, int4 q1, float s, float z) {
  __half hs = __float2half(s);
  __half2 s2 = __halves2half2(hs, hs);
  __half hc = __float2half(-(64.f + z) * s);
  __half2 c2 = __halves2half2(hc, hc);
  uint32_t b0 = 0x54005400u + ((uint32_t)q0.x << 4) + ((uint32_t)q0.y << 20);
  uint32_t b1 = 0x54005400u + ((uint32_t)q0.z << 4) + ((uint32_t)q0.w << 20);
  uint32_t b2 = 0x54005400u + ((uint32_t)q1.x << 4) + ((uint32_t)q1.y << 20);
  uint32_t b3 = 0x54005400u + ((uint32_t)q1.z << 4) + ((uint32_t)q1.w << 20);
  union { s16x8 v; __half2 h2[4]; } w;
  w.h2[0] = __hfma2(*(__half2*)&b0, s2, c2);
  w.h2[1] = __hfma2(*(__half2*)&b1, s2, c2);
  w.h2[2] = __hfma2(*(__half2*)&b2, s2, c2);
  w.h2[3] = __hfma2(*(__half2*)&b3, s2, c2);
  return w.v;
}

// 8 weights from one packed u32 (nibbles ascending)
__device__ __forceinline__ s16x8 dq8(uint32_t w, __half2 s2, __half2 c2) {
  union { s16x8 v; __half2 h2[4]; } r;
#pragma unroll
  for (int i = 0; i < 4; ++i) {
    uint32_t t = (w >> (8 * i)) & 0xFFu;
    uint32_t b = 0x54005400u + ((t & 15u) << 4) + ((t >> 4) << 20);
    r.h2[i] = __hfma2(*(__half2*)&b, s2, c2);
  }
  return r.v;
}

// bijective XCD swizzle (m204)
__device__ __forceinline__ int xcd_swz(int w0, int nwg) {
  const int q = nwg >> 3, r = nwg & 7;
  const int xcd = w0 & 7, idx = w0 >> 3;
  const int base = (xcd < r) ? xcd * (q + 1) : r * (q + 1) + (xcd - r) * q;
  return base + idx;
}

// ---------------------------------------------------------------------------
// gate/up GEMM (r11 structure, PK adds 4-bit packed weight loads).
// EPI=0: Pan = fp16(acc).  EPI=1: Pan = silu(Pan) * acc  (in-place h)
// BM=256, BN=128, BK=64. 512 thr (8 waves: 4M x 2N, 64x64 each).
// 2-deep register prefetch (two named sets), dbuf LDS.
// ---------------------------------------------------------------------------
template <int EPI, int PK>
__global__ __launch_bounds__(512, 2)
void qgemm_x_kernel(const __half* __restrict__ Xh,
                    const int* __restrict__ Q, const uint32_t* __restrict__ QP,
                    const float* __restrict__ S, const float* __restrict__ Z,
                    __half* __restrict__ Pan, int mbs) {
  constexpr int H = 4096, I = 11008, G = 32;
  const int wg = xcd_swz(blockIdx.x, gridDim.x);
  const int mb = wg % mbs;          // mb fastest: neighbors share the W panel
  const int nb = wg / mbs;
  const int m0 = mb * 256;
  const int n0 = nb * 128;
  const int tid = threadIdx.x;
  const int lane = tid & 63;
  const int wave = tid >> 6;
  const int wm = (wave >> 1) * 64, wn = (wave & 1) * 64;
  const int l15 = lane & 15, lq = lane >> 4;
  const int rsw = (l15 & 7) << 3;

  __shared__ __half As[2][256][64];   // 64 KB
  __shared__ __half Bs[2][128][64];   // 32 KB

  f32x4 acc[4][4];
#pragma unroll
  for (int i = 0; i < 4; ++i)
#pragma unroll
    for (int j = 0; j < 4; ++j) acc[i][j] = {0.f, 0.f, 0.f, 0.f};

  // staging maps
  const int arow = tid >> 1, acol0 = (tid & 1) * 32, asw = (arow & 7) << 3;
  const int qrow = tid >> 2, qcol0 = (tid & 3) * 16, qsw = (qrow & 7) << 3;
  const __half*   aP  = Xh + (size_t)(m0 + arow) * H + acol0;
  const int*      qP  = Q  + (size_t)(n0 + qrow) * H + qcol0;
  const uint32_t* qPp = QP + (size_t)(n0 + qrow) * (H / 8) + (tid & 3) * 2;
  const float*    sP  = S + (size_t)(n0 + qrow) * G;
  const float*    zP  = Z + (size_t)(n0 + qrow) * G;

  // two named prefetch sets (static indexing)
  s16x8 aA[4], aB[4];
  int4  qA[4], qB[4];
  uint32_t wA0, wA1, wB0, wB1;
  float sA, zA, sB, zB;

#define LOAD_SET(set, kk)                                         \
  {                                                               \
    const int _k = (kk);                                          \
    _Pragma("unroll")                                             \
    for (int i = 0; i < 4; ++i) a##set[i] = ((const s16x8*)(aP + _k))[i]; \
    if (PK) {                                                     \
      w##set##0 = qPp[_k >> 3]; w##set##1 = qPp[(_k >> 3) + 1];   \
    } else {                                                      \
      _Pragma("unroll")                                           \
      for (int i = 0; i < 4; ++i) q##set[i] = ((const int4*)(qP + _k))[i]; \
    }                                                             \
    s##set = sP[_k >> 7]; z##set = zP[_k >> 7];                   \
  }
#define WRITE_SET(buf, set)                                       \
  {                                                               \
    _Pragma("unroll")                                             \
    for (int i = 0; i < 4; ++i)                                   \
      *(s16x8*)&As[buf][arow][(acol0 + i * 8) ^ asw] = a##set[i]; \
    if (PK) {                                                     \
      __half hs = __float2half(s##set);                           \
      __half2 s2 = __halves2half2(hs, hs);                        \
      __half hc = __float2half(-(64.f + z##set) * s##set);        \
      __half2 c2 = __halves2half2(hc, hc);                        \
      *(s16x8*)&Bs[buf][qrow][(qcol0 + 0) ^ qsw] = dq8(w##set##0, s2, c2); \
      *(s16x8*)&Bs[buf][qrow][(qcol0 + 8) ^ qsw] = dq8(w##set##1, s2, c2); \
    } else {                                                      \
      *(s16x8*)&Bs[buf][qrow][(qcol0 + 0) ^ qsw] = dq_compute(q##set[0], q##set[1], s##set, z##set); \
      *(s16x8*)&Bs[buf][qrow][(qcol0 + 8) ^ qsw] = dq_compute(q##set[2], q##set[3], s##set, z##set); \
    }                                                             \
  }
#define MFMA_BUF(buf)                                             \
  {                                                               \
    __builtin_amdgcn_s_setprio(1);                                \
    _Pragma("unroll")                                             \
    for (int kk = 0; kk < 2; ++kk) {                              \
      const int cbase = (kk * 32 + lq * 8) ^ rsw;                 \
      f16x8 af[4];                                                \
      _Pragma("unroll")                                           \
      for (int i = 0; i < 4; ++i)                                 \
        af[i] = *(const f16x8*)&As[buf][wm + i * 16 + l15][cbase];\
      _Pragma("unroll")                                           \
      for (int j = 0; j < 4; ++j) {                               \
        f16x8 bf = *(const f16x8*)&Bs[buf][wn + j * 16 + l15][cbase]; \
        _Pragma("unroll")                                         \
        for (int i = 0; i < 4; ++i)                               \
          acc[i][j] = __builtin_amdgcn_mfma_f32_16x16x32_f16(af[i], bf, acc[i][j], 0, 0, 0); \
      }                                                           \
    }                                                             \
    __builtin_amdgcn_s_setprio(0);                                \
  }

  const int nt = H / 64;  // 64, even
  LOAD_SET(A, 0)
  LOAD_SET(B, 64)
  WRITE_SET(0, A)
  __syncthreads();

  for (int t = 0; t < nt; t += 2) {
    if (t + 2 < nt) LOAD_SET(A, (t + 2) * 64)
    MFMA_BUF(0)
    WRITE_SET(1, B)
    __syncthreads();
    if (t + 3 < nt) LOAD_SET(B, (t + 3) * 64)
    MFMA_BUF(1)
    if (t + 2 < nt) WRITE_SET(0, A)
    __syncthreads();
  }
#undef LOAD_SET
#undef WRITE_SET
#undef MFMA_BUF

  // ---- epilogue ----
#pragma unroll
  for (int i = 0; i < 4; ++i)
#pragma unroll
    for (int j = 0; j < 4; ++j)
#pragma unroll
      for (int r = 0; r < 4; ++r) {
        const int row = m0 + wm + i * 16 + lq * 4 + r;
        const int col = n0 + wn + j * 16 + l15;
        const size_t idx = (size_t)row * I + col;
        if (EPI == 0) {
          Pan[idx] = __float2half(acc[i][j][r]);
        } else {
          float g = __half2float(Pan[idx]);
          float u = acc[i][j][r];
          Pan[idx] = __float2half((g / (1.f + __expf(-g))) * u);
        }
      }
}

// ---------------------------------------------------------------------------
// Down GEMM (r11 structure + PK). out = h @ Wd^T. K=11008.
// ---------------------------------------------------------------------------
template <int PK>
__global__ __launch_bounds__(512, 2)
void down_kernel(const __half* __restrict__ Hws,
                 const int* __restrict__ Qd, const uint32_t* __restrict__ QdP,
                 const float* __restrict__ Sd, const float* __restrict__ Zd,
                 float* __restrict__ Out, int mbs) {
  constexpr int K = 11008, N = 4096, G = 86;
  const int wg = xcd_swz(blockIdx.x, gridDim.x);
  const int mb = wg % mbs;
  const int nb = wg / mbs;
  const int m0 = mb * 256, n0 = nb * 128;
  const int tid = threadIdx.x;
  const int lane = tid & 63;
  const int wave = tid >> 6;
  const int wm = (wave >> 1) * 64, wn = (wave & 1) * 64;
  const int l15 = lane & 15, lq = lane >> 4;
  const int rsw = (l15 & 7) << 3;

  __shared__ __half As[2][256][64];
  __shared__ __half Bs[2][128][64];

  f32x4 acc[4][4];
#pragma unroll
  for (int i = 0; i < 4; ++i)
#pragma unroll
    for (int j = 0; j < 4; ++j) acc[i][j] = {0.f, 0.f, 0.f, 0.f};

  const int arow = tid >> 1, acol0 = (tid & 1) * 32, asw = (arow & 7) << 3;
  const int qrow = tid >> 2, qcol0 = (tid & 3) * 16, qsw = (qrow & 7) << 3;
  const __half*   aP  = Hws + (size_t)(m0 + arow) * K + acol0;
  const int*      qP  = Qd  + (size_t)(n0 + qrow) * K + qcol0;
  const uint32_t* qPp = QdP + (size_t)(n0 + qrow) * (K / 8) + (tid & 3) * 2;
  const float*    sP  = Sd + (size_t)(n0 + qrow) * G;
  const float*    zP  = Zd + (size_t)(n0 + qrow) * G;

  s16x8 aA[4], aB[4];
  int4  qA[4], qB[4];
  uint32_t wA0, wA1, wB0, wB1;
  float sA, zA, sB, zB;

#define LOAD_SET(set, kk)                                         \
  {                                                               \
    const int _k = (kk);                                          \
    _Pragma("unroll")                                             \
    for (int i = 0; i < 4; ++i) a##set[i] = ((const s16x8*)(aP + _k))[i]; \
    if (PK) {                                                     \
      w##set##0 = qPp[_k >> 3]; w##set##1 = qPp[(_k >> 3) + 1];   \
    } else {                                                      \
      _Pragma("unroll")                                           \
      for (int i = 0; i < 4; ++i) q##set[i] = ((const int4*)(qP + _k))[i]; \
    }                                                             \
    s##set = sP[_k >> 7]; z##set = zP[_k >> 7];                   \
  }
#define WRITE_SET(buf, set)                                       \
  {                                                               \
    _Pragma("unroll")                                             \
    for (int i = 0; i < 4; ++i)                                   \
      *(s16x8*)&As[buf][arow][(acol0 + i * 8) ^ asw] = a##set[i]; \
    if (PK) {                                                     \
      __half hs = __float2half(s##set);                           \
      __half2 s2 = __halves2half2(hs, hs);                        \
      __half hc = __float2half(-(64.f + z##set) * s##set);        \
      __half2 c2 = __halves2half2(hc, hc);                        \
      *(s16x8*)&Bs[buf][qrow][(qcol0 + 0) ^ qsw] = dq8(w##set##0, s2, c2); \
      *(s16x8*)&Bs[buf][qrow][(qcol0 + 8) ^ qsw] = dq8(w##set##1, s2, c2); \
    } else {                                                      \
      *(s16x8*)&Bs[buf][qrow][(qcol0 + 0) ^ qsw] = dq_compute(q##set[0], q##set[1], s##set, z##set); \
      *(s16x8*)&Bs[buf][qrow][(qcol0 + 8) ^ qsw] = dq_compute(q##set[2], q##set[3], s##set, z##set); \
    }                                                             \
  }
#define MFMA_BUF(buf)                                             \
  {                                                               \
    __builtin_amdgcn_s_setprio(1);                                \
    _Pragma("unroll")                                             \
    for (int kk = 0; kk < 2; ++kk) {                              \
      const int cbase = (kk * 32 + lq * 8) ^ rsw;                 \
      f16x8 af[4];                                                \
      _Pragma("unroll")                                           \
      for (int i = 0; i < 4; ++i)                                 \
        af[i] = *(const f16x8*)&As[buf][wm + i * 16 + l15][cbase];\
      _Pragma("unroll")                                           \
      for (int j = 0; j < 4; ++j) {                               \
        f16x8 bf = *(const f16x8*)&Bs[buf][wn + j * 16 + l15][cbase]; \
        _Pragma("unroll")                                         \
        for (int i = 0; i < 4; ++i)                               \
          acc[i][j] = __builtin_amdgcn_mfma_f32_16x16x32_f16(af[i], bf, acc[i][j], 0, 0, 0); \
      }                                                           \
    }                                                             \
    __builtin_amdgcn_s_setprio(0);                                \
  }

  const int nt = K / 64;  // 172, even
  LOAD_SET(A, 0)
  LOAD_SET(B, 64)
  WRITE_SET(0, A)
  __syncthreads();

  for (int t = 0; t < nt; t += 2) {
    if (t + 2 < nt) LOAD_SET(A, (t + 2) * 64)
    MFMA_BUF(0)
    WRITE_SET(1, B)
    __syncthreads();
    if (t + 3 < nt) LOAD_SET(B, (t + 3) * 64)
    MFMA_BUF(1)
    if (t + 2 < nt) WRITE_SET(0, A)
    __syncthreads();
  }
#undef LOAD_SET
#undef WRITE_SET
#undef MFMA_BUF

#pragma unroll
  for (int i = 0; i < 4; ++i)
#pragma unroll
    for (int j = 0; j < 4; ++j)
#pragma unroll
      for (int r = 0; r < 4; ++r) {
        const int row = m0 + wm + i * 16 + lq * 4 + r;
        const int col = n0 + wn + j * 16 + l15;
        Out[(size_t)row * N + col] = acc[i][j][r];
      }
}

// ---------------------------------------------------------------------------
extern "C" void kernel_launch(void* const* d_in, const int* in_sizes, int n_in,
                              void* d_out, int out_size, void* d_ws, size_t ws_size,
                              hipStream_t stream) {
  const float* x  = (const float*)d_in[0];
  const int* qg   = (const int*)d_in[1];
  const int* qu   = (const int*)d_in[2];
  const int* qd   = (const int*)d_in[3];
  const float* sg = (const float*)d_in[4];
  const float* zg = (const float*)d_in[5];
  const float* su = (const float*)d_in[6];
  const float* zu = (const float*)d_in[7];
  const float* sd = (const float*)d_in[8];
  const float* zd = (const float*)d_in[9];
  float* out = (float*)d_out;

  const int M = 8192, H = 4096, I = 11008;
  const long N8 = (long)I * H / 8;       // 5,636,096 u32 = 1376 out-rows each
  const int PG_ROW = 4064;               // Pg at rows 4064..5439
  const int PU_ROW = PG_ROW + 1376;      // Pu at rows 5440..6815
  const int PD_ROW = PU_ROW + 1376;      // Pd at rows 6816..8191

  uint32_t* Pg = (uint32_t*)((char*)d_out + (size_t)PG_ROW * H * 4);
  uint32_t* Pu = Pg + N8;
  uint32_t* Pd = Pu + N8;

  pack_kernel<<<2048, 256, 0, stream>>>(qg, Pg, N8);
  pack_kernel<<<2048, 256, 0, stream>>>(qu, Pu, N8);
  pack_kernel<<<2048, 256, 0, stream>>>(qd, Pd, N8);

  // M-chunking: x fp16 chunk + h panel chunk in ws. Mc multiple of 256.
  const size_t per_row = (size_t)(H + I) * 2;
  long mc = (long)(ws_size / per_row);
  mc &= ~255L;
  if (mc > M) mc = M;
  if (mc < 256) mc = 256;
  const int Mc = (int)mc;

  __half* wsx = (__half*)d_ws;
  __half* wsh = (__half*)((char*)d_ws + (size_t)Mc * H * 2);

  for (int mbase = 0; mbase < M; mbase += Mc) {
    const int rows = (M - mbase < Mc) ? (M - mbase) : Mc;
    const int mbs = rows / 256;
    // Packed usability: prior chunks' down wrote rows [0, mbase); a packed
    // buffer is readable iff that stayed below its start row. down must also
    // not overwrite the region it reads during this chunk.
    const bool g_pk = (mbase <= PG_ROW);
    const bool u_pk = (mbase <= PU_ROW);
    const bool d_pk = (mbase + rows <= PD_ROW);

    cvt_f32_to_f16_kernel<<<1024, 256, 0, stream>>>(
        x + (size_t)mbase * H, wsx, (long)rows * H);

    if (g_pk)
      qgemm_x_kernel<0, 1><<<mbs * (I / 128), 512, 0, stream>>>(
          wsx, qg, Pg, sg, zg, wsh, mbs);
    else
      qgemm_x_kernel<0, 0><<<mbs * (I / 128), 512, 0, stream>>>(
          wsx, qg, Pg, sg, zg, wsh, mbs);

    if (u_pk)
      qgemm_x_kernel<1, 1><<<mbs * (I / 128), 512, 0, stream>>>(
          wsx, qu, Pu, su, zu, wsh, mbs);
    else
      qgemm_x_kernel<1, 0><<<mbs * (I / 128), 512, 0, stream>>>(
          wsx, qu, Pu, su, zu, wsh, mbs);

    if (d_pk)
      down_kernel<1><<<mbs * (H / 128), 512, 0, stream>>>(
          wsh, qd, Pd, sd, zd, out + (size_t)mbase * H, mbs);
    else
      down_kernel<0><<<mbs * (H / 128), 512, 0, stream>>>(
          wsh, qd, Pd, sd, zd, out + (size_t)mbase * H, mbs);
  }
}